// Round 9
// baseline (99.894 us; speedup 1.0000x reference)
//
#include <hip/hip_runtime.h>
#include <hip/hip_fp16.h>

// ---------------- problem constants ----------------
#define NIMG 32
#define CH   3
#define HIN  256
#define WIN  256
#define MARG 38          // 2*HZ_PAD + 32
#define HP   332         // HIN + 2*MARG
#define WP   332
#define HU   664         // 2*HP
#define WU   664
#define HO   256
#define WO   256

// plain fp16 upsampled intermediate, padded row pitch (cols 664..671 are zeros)
#define UPITCH  672
#define CHELEMS (664 * 672)

// LDS staging window for the warp (per 32x32 output tile)
#define PH 132            // max rows
#define PW 152            // max cols (19 x 8-elem slots), 8-aligned base
#define PWB (PW * 2)      // row pitch in bytes (304)

typedef __fp16 h2 __attribute__((ext_vector_type(2)));
typedef float  f2 __attribute__((ext_vector_type(2)));

// reflect (edge-excluding) for original 256-range, valid for r in [-255, 510]
__device__ __forceinline__ int refl(int r) {
    r = (r < 0) ? -r : r;
    return (r > 255) ? (510 - r) : r;
}

// ---------------- per-image affine coefficients ----------------
__global__ void k_setup(const float* __restrict__ th, const float* __restrict__ ls,
                        const float* __restrict__ txp, const float* __restrict__ typ,
                        float* __restrict__ coef) {
    int n = blockIdx.x * blockDim.x + threadIdx.x;
    if (n >= NIMG) return;
    float c  = cosf(th[n]);
    float sn = sinf(th[n]);
    float inv_s = 1.0f / expf(ls[n]);
    float tX = -txp[n] * (float)WIN;
    float tY = -typ[n] * (float)HIN;
    float A00 = inv_s * c,    A01 = inv_s * sn,  A02 = inv_s * (c * tX + sn * tY);
    float A10 = -inv_s * sn,  A11 = inv_s * c,   A12 = inv_s * (-sn * tX + c * tY);
    A02 *= 2.0f; A12 *= 2.0f;
    A02 += 0.5f * (A00 + A01) - 0.5f;
    A12 += 0.5f * (A10 + A11) - 0.5f;
    const float Wu = (float)HU, Hu = (float)HU;
    const float Wt = 524.0f, Ht = 524.0f;
    float B00 = A00 * (2.0f / Wu) * (Wt * 0.5f);
    float B01 = A01 * (2.0f / Wu) * (Ht * 0.5f);
    float B02 = A02 * (2.0f / Wu);
    float B10 = A10 * (2.0f / Hu) * (Wt * 0.5f);
    float B11 = A11 * (2.0f / Hu) * (Ht * 0.5f);
    float B12 = A12 * (2.0f / Hu);
    float cxx = B00 * Wu / Wt;
    float cxy = B01 * Wu / Ht;
    float cx0 = 0.5f * ((B00 * (1.0f / Wt - 1.0f) + B01 * (1.0f / Ht - 1.0f) + B02 + 1.0f) * Wu - 1.0f);
    float cyx = B10 * Hu / Wt;
    float cyy = B11 * Hu / Ht;
    float cy0 = 0.5f * ((B10 * (1.0f / Wt - 1.0f) + B11 * (1.0f / Ht - 1.0f) + B12 + 1.0f) * Hu - 1.0f);
    coef[n * 6 + 0] = cxx;
    coef[n * 6 + 1] = cxy;
    coef[n * 6 + 2] = cx0;
    coef[n * 6 + 3] = cyx;
    coef[n * 6 + 4] = cyy;
    coef[n * 6 + 5] = cy0;
}

__device__ __forceinline__ unsigned hbits(float a, float b) {
    __half2 h = __floats2half2_rn(a, b);
    return *(unsigned*)&h;
}

// ---------------- KA: fused reflect-pad + 2x upsample -> plain fp16 (padded pitch) ----------------
// Stage-1: interior blocks (no reflect, no bounds — block-uniform) load direct.
// Stage-2: row-pairs packed f32 (7 ds_read2 per item).
// Stage-3: single pass, 8 cols/thread: 7 x b128 LDS reads + 2 x 16B global stores.
__global__ void __launch_bounds__(256) k_up2(const float* __restrict__ img,
                                             const float* __restrict__ hz,
                                             __fp16* __restrict__ ups, int ch0) {
    __shared__ float    s_in[38][40];     // 38 rows x 39 cols used (6.1 KB)
    __shared__ unsigned s_midh[38][36];   // h2 (even,odd); cols 0..32 used; 16B-aligned pitch
    int ch  = blockIdx.z;
    int ty0 = blockIdx.y * 64;
    int tx0 = blockIdx.x * 64;
    int jy0 = (ty0 >> 1) - 3;
    int jx0 = (tx0 >> 1) - 3;
    int tid = threadIdx.x;
    float fs[12];                     // 2*f[i] (exact scaling)
#pragma unroll
    for (int i = 0; i < 12; ++i) fs[i] = 2.0f * hz[i];
    const float* base = img + (size_t)(ch0 + ch) * HIN * WIN;

    // stage 1: padded input patch (38 x 39), zero outside [0,332)^2
    if (jy0 >= 38 && jy0 <= 256 && jx0 >= 38 && jx0 <= 255) {
        // interior: whole patch maps 1:1, no reflect/bounds (block-uniform branch)
        const float* bsrc = base + (jy0 - MARG) * WIN + (jx0 - MARG);
        for (int i = tid; i < 38 * 39; i += 256) {
            int ly = i / 39, lx = i - ly * 39;
            s_in[ly][lx] = bsrc[ly * WIN + lx];
        }
    } else {
        for (int i = tid; i < 38 * 39; i += 256) {
            int ly = i / 39, lx = i - ly * 39;
            int gy = jy0 + ly, gx = jx0 + lx;
            float v = 0.0f;
            if (gy >= 0 && gy < HP && gx >= 0 && gx < WP)
                v = base[refl(gy - MARG) * WIN + refl(gx - MARG)];
            s_in[ly][lx] = v;
        }
    }
    __syncthreads();

    // stage 2: horizontal upsample, row-pairs packed; 7 ds_read2 per item (t reuse)
    for (int i = tid; i < 19 * 33; i += 256) {
        int j = i % 33, lp = i / 33;
        int ly = 2 * lp;
        const float* ra = &s_in[ly][j];
        const float* rb = &s_in[ly + 1][j];
        f2 t0; t0.x = ra[0]; t0.y = rb[0];
        f2 t1; t1.x = ra[1]; t1.y = rb[1];
        f2 t2; t2.x = ra[2]; t2.y = rb[2];
        f2 t3; t3.x = ra[3]; t3.y = rb[3];
        f2 t4; t4.x = ra[4]; t4.y = rb[4];
        f2 t5; t5.x = ra[5]; t5.y = rb[5];
        f2 t6; t6.x = ra[6]; t6.y = rb[6];
        f2 ev = fs[11]*t0 + fs[9]*t1 + fs[7]*t2 + fs[5]*t3 + fs[3]*t4 + fs[1]*t5;
        f2 od = fs[10]*t1 + fs[8]*t2 + fs[6]*t3 + fs[4]*t4 + fs[2]*t5 + fs[0]*t6;
        s_midh[ly][j]     = hbits(ev.x, od.x);    // (even,odd) = up cols (2j, 2j+1)
        s_midh[ly + 1][j] = hbits(ev.y, od.y);
    }
    __syncthreads();

    // stage 3: vertical upsample; single pass, 8 up-cols per thread
    {
        int qx8 = tid & 7;            // col-group: up cols 8*qx8 .. 8*qx8+7
        int m   = tid >> 3;           // row-pair 0..31
        int gx0 = tx0 + 8 * qx8;
        int gy  = ty0 + 2 * m;
        __fp16* upch = ups + (size_t)ch * CHELEMS;
        if (gy < HU) {
            if (gx0 + 7 < WU) {
                const uint4* mp = (const uint4*)&s_midh[m][4 * qx8];   // 9 uint4 per row
                uint4 u = mp[0];
                float e0=0.f,e1=0.f,e2=0.f,e3=0.f,e4=0.f,e5=0.f,e6=0.f,e7=0.f;
                float o0=0.f,o1=0.f,o2=0.f,o3=0.f,o4=0.f,o5=0.f,o6=0.f,o7=0.f;
#pragma unroll
                for (int t = 0; t < 6; ++t) {
                    uint4 un = mp[(t + 1) * 9];
                    float fe = fs[11 - 2 * t];
                    float fo = fs[10 - 2 * t];
                    h2 a0; *(unsigned*)&a0 = u.x;
                    h2 a1; *(unsigned*)&a1 = u.y;
                    h2 a2; *(unsigned*)&a2 = u.z;
                    h2 a3; *(unsigned*)&a3 = u.w;
                    e0 += fe * (float)a0[0]; e1 += fe * (float)a0[1];
                    e2 += fe * (float)a1[0]; e3 += fe * (float)a1[1];
                    e4 += fe * (float)a2[0]; e5 += fe * (float)a2[1];
                    e6 += fe * (float)a3[0]; e7 += fe * (float)a3[1];
                    h2 b0; *(unsigned*)&b0 = un.x;
                    h2 b1; *(unsigned*)&b1 = un.y;
                    h2 b2; *(unsigned*)&b2 = un.z;
                    h2 b3; *(unsigned*)&b3 = un.w;
                    o0 += fo * (float)b0[0]; o1 += fo * (float)b0[1];
                    o2 += fo * (float)b1[0]; o3 += fo * (float)b1[1];
                    o4 += fo * (float)b2[0]; o5 += fo * (float)b2[1];
                    o6 += fo * (float)b3[0]; o7 += fo * (float)b3[1];
                    u = un;
                }
                uint4 qe, qo;
                qe.x = hbits(e0, e1); qe.y = hbits(e2, e3);
                qe.z = hbits(e4, e5); qe.w = hbits(e6, e7);
                qo.x = hbits(o0, o1); qo.y = hbits(o2, o3);
                qo.z = hbits(o4, o5); qo.w = hbits(o6, o7);
                *(uint4*)&upch[(size_t)gy * UPITCH + gx0]       = qe;
                *(uint4*)&upch[(size_t)(gy + 1) * UPITCH + gx0] = qo;
            } else if (gx0 >= WU && gx0 < UPITCH) {
                uint4 z; z.x = 0u; z.y = 0u; z.z = 0u; z.w = 0u;   // pad cols 664..671
                *(uint4*)&upch[(size_t)gy * UPITCH + gx0]       = z;
                *(uint4*)&upch[(size_t)(gy + 1) * UPITCH + gx0] = z;
            }
        }
    }
}

// ---------------- gather helpers ----------------
// act-free: out-of-tile samples (lwy/lwx in [74,80)) write into s_wh's padding
// (max waddr 79*82+79 = 6557 < 6560), which ph2 never reads (rows<74, cols<=73).
struct GS {
    int a_rd;        // clamped LDS byte addr of (ly, e) halfword pair
    unsigned sh;     // alignbit shift (0 or 16)
    int waddr;       // s_wh element index
    float wyf;       // y lerp weight
    h2 wv;           // packed (1-wx, wx)
};

__device__ __forceinline__ GS gmake(float rx, float ry, int wadd) {
    GS g;
    int lx = (int)rx;                               // trunc == floor (rx>=0 when in-tile)
    int ly = (int)ry;
    float wx = __builtin_amdgcn_fractf(rx);         // == rx - floor(rx); exact, 1 instr
    g.wyf    = __builtin_amdgcn_fractf(ry);
    unsigned a = (unsigned)(ly * PWB + (lx & ~1) * 2);
    const unsigned amax = (PH - 1) * PWB - 8;
    g.a_rd = (int)(a > amax ? amax : a);            // single v_min_u32: negatives wrap huge
    g.sh = ((unsigned)lx & 1u) << 4;
    g.waddr = wadd;
    g.wv = __builtin_amdgcn_cvt_pkrtz(1.0f - wx, wx);
    return g;
}

__device__ __forceinline__ void gfinish(const GS& g, unsigned w0, unsigned w1,
                                        unsigned w2, unsigned w3, __fp16* s_wh) {
    unsigned u0 = __builtin_amdgcn_alignbit(w1, w0, g.sh);
    unsigned u1 = __builtin_amdgcn_alignbit(w3, w2, g.sh);
    h2 h0; *(unsigned*)&h0 = u0;
    h2 h1; *(unsigned*)&h1 = u1;
    float r0 = __builtin_amdgcn_fdot2(h0, g.wv, 0.0f, false);
    float r1 = __builtin_amdgcn_fdot2(h1, g.wv, 0.0f, false);
    s_wh[g.waddr] = (__fp16)(r0 + g.wyf * (r1 - r0));   // unconditional
}

// ---------------- KB: LDS-staged bilinear warp + 2x downsample (512 threads) ----------------
__global__ void __launch_bounds__(512) k_warpdn(const __fp16* __restrict__ ups,
                                                const float* __restrict__ coef,
                                                const float* __restrict__ hz,
                                                float* __restrict__ out,
                                                int n0, int ch0) {
    __shared__ __align__(16) unsigned char s_raw[PH * PWB];      // 40.1 KB
    __shared__ __fp16 s_wh[80 * 82];                             // 13.1 KB
    __fp16* s_src = (__fp16*)s_raw;
    h2*     s_m2  = (h2*)s_raw;      // aliases s_src (disjoint live ranges)

    int ch  = blockIdx.z;
    int ty0 = blockIdx.y * 32;
    int tx0 = blockIdx.x * 32;
    int tid = threadIdx.x;
    const float* cf = coef + (size_t)(n0 + ch / CH) * 6;
    float cxx = cf[0], cxy = cf[1], cx0 = cf[2];
    float cyx = cf[3], cyy = cf[4], cy0 = cf[5];
    const __fp16* upc = ups + (size_t)ch * CHELEMS;
    const unsigned short* us = (const unsigned short*)upc;
    int wy0 = 2 * ty0 + 1, wx0 = 2 * tx0 + 1;
    float wx0f = (float)wx0, wy0f = (float)wy0;

    // source bbox from tile corners (affine -> corners bound everything)
    float ix00 = cxx * wx0f + cxy * wy0f + cx0;
    float iy00 = cyx * wx0f + cyy * wy0f + cy0;
    float dxx = cxx * 73.0f, dxy = cxy * 73.0f;
    float dyx = cyx * 73.0f, dyy = cyy * 73.0f;
    float ixmin = ix00 + fminf(dxx, 0.0f) + fminf(dxy, 0.0f);
    float ixmax = ix00 + fmaxf(dxx, 0.0f) + fmaxf(dxy, 0.0f);
    float iymin = iy00 + fminf(dyx, 0.0f) + fminf(dyy, 0.0f);
    float iymax = iy00 + fmaxf(dyx, 0.0f) + fmaxf(dyy, 0.0f);
    int x_lo = (int)floorf(ixmin) - 1;
    int x_base = x_lo & ~7;
    int x_hi = (int)floorf(ixmax) + 2;
    int y_lo = (int)floorf(iymin) - 1;
    int y_hi = (int)floorf(iymax) + 2;
    int Rn = y_hi - y_lo + 1;
    int Wn = x_hi - x_base + 1;
    bool ldsok = (Rn <= PH) && (Wn <= PW);

    int wave = __builtin_amdgcn_readfirstlane(tid >> 6);   // 0..7
    int lane = tid & 63;
    int ply = lane >> 3, plx = lane & 7;
    float ix_l = cxx * (float)(wx0 + plx) + cxy * (float)(wy0 + ply) + cx0;
    float iy_l = cyx * (float)(wx0 + plx) + cyy * (float)(wy0 + ply) + cy0;
    float c8xx = 8.0f * cxx, c8xy = 8.0f * cxy;
    float c8yx = 8.0f * cyx, c8yy = 8.0f * cyy;

    if (ldsok) {
        // ---- stage bbox into LDS, dense per-lane (row,slot) mapping ----
        int spr = (Wn + 7) >> 3;                  // slots per row, <= 19
        int rpp = 64 / spr;                       // rows per wave-pass
        float rcp = 1.0f / (float)spr;
        int lrow = (int)((float)lane * rcp);
        if (lrow * spr > lane) lrow--;
        if ((lrow + 1) * spr <= lane) lrow++;
        int lslot = lane - lrow * spr;
        if (lrow < rpp) {
            int gx = x_base + lslot * 8;
            for (int row = wave * rpp + lrow; row < Rn; row += 8 * rpp) {
                int gy = y_lo + row;
                uint4 val;
                if (gy >= 0 && gy < HU && gx >= 0 && gx <= UPITCH - 8) {
                    val = *(const uint4*)&upc[(size_t)gy * UPITCH + gx];
                } else if (gy >= 0 && gy < HU) {
                    unsigned part[4];
#pragma unroll
                    for (int k = 0; k < 4; ++k) {
                        int ga = gx + 2 * k, gb = ga + 1;
                        unsigned lo = (ga >= 0 && ga < WU) ? (unsigned)us[(size_t)gy * UPITCH + ga] : 0u;
                        unsigned hi = (gb >= 0 && gb < WU) ? (unsigned)us[(size_t)gy * UPITCH + gb] : 0u;
                        part[k] = lo | (hi << 16);
                    }
                    val.x = part[0]; val.y = part[1]; val.z = part[2]; val.w = part[3];
                } else {
                    val.x = 0u; val.y = 0u; val.z = 0u; val.w = 0u;
                }
                *(uint4*)&s_src[row * PW + lslot * 8] = val;
            }
        }
        __syncthreads();

        // ---- warp from LDS: depth-2 pipelined, column-major incremental stepping ----
        float ixb = ix_l - (float)x_base;
        float iyb = iy_l - (float)y_lo;
        int wbase = ply * 82 + plx;
        float rx = ixb + (float)wave * c8xy;          // px=0, py=wave
        float ry = iyb + (float)wave * c8yy;
        int wadd = wbase + wave * 656;
        int py = wave;
        const float sxA = 8.0f * c8xy,            syA = 8.0f * c8yy;
        const float sxB = c8xx - 2.0f * c8xy,     syB = c8yx - 2.0f * c8yy;
        int tc = (wave < 4) ? 13 : 12;            // idx = wave + 8k < 100

        GS g0 = gmake(rx, ry, wadd);
        {   int pyn = py + 8;
            if (pyn >= 10) { rx += sxB; ry += syB; wadd += 8 - 2 * 656; py = pyn - 10; }
            else           { rx += sxA; ry += syA; wadd += 8 * 656;     py = pyn; } }
        const unsigned* q0 = (const unsigned*)(s_raw + g0.a_rd);
        unsigned a0 = q0[0], a1 = q0[1], a2 = q0[PWB / 4], a3 = q0[PWB / 4 + 1];
        for (int k = 1; k < tc; ++k) {
            GS g1 = gmake(rx, ry, wadd);
            {   int pyn = py + 8;
                if (pyn >= 10) { rx += sxB; ry += syB; wadd += 8 - 2 * 656; py = pyn - 10; }
                else           { rx += sxA; ry += syA; wadd += 8 * 656;     py = pyn; } }
            const unsigned* q1 = (const unsigned*)(s_raw + g1.a_rd);
            unsigned b0 = q1[0], b1 = q1[1], b2 = q1[PWB / 4], b3 = q1[PWB / 4 + 1];
            gfinish(g0, a0, a1, a2, a3, s_wh);
            g0 = g1; a0 = b0; a1 = b1; a2 = b2; a3 = b3;
        }
        gfinish(g0, a0, a1, a2, a3, s_wh);
    } else {
        // ---- fallback: guarded global gather (rare: bbox too large) ----
        for (int pp = wave; pp < 100; pp += 8) {
            int py = (pp * 205) >> 11;
            int px = pp - py * 10;
            int lwy = py * 8 + ply;
            int lwx = px * 8 + plx;
            if (lwy < 74 && lwx < 74) {
                float ix = ix_l + (float)px * c8xx + (float)py * c8xy;
                float iy = iy_l + (float)px * c8yx + (float)py * c8yy;
                float fx = floorf(ix), fy = floorf(iy);
                float wx = ix - fx, wyf = iy - fy;
                int x0 = (int)fx, y0 = (int)fy;
                int xc0 = min(max(x0, 0), WU - 1);
                int xc1 = min(max(x0 + 1, 0), WU - 1);
                int yc0 = min(max(y0, 0), HU - 1);
                int yc1 = min(max(y0 + 1, 0), HU - 1);
                float mx0 = (x0 >= 0 && x0 < WU) ? 1.0f : 0.0f;
                float mx1 = (x0 >= -1 && x0 < WU - 1) ? 1.0f : 0.0f;
                float my0 = (y0 >= 0 && y0 < HU) ? 1.0f : 0.0f;
                float my1 = (y0 >= -1 && y0 < HU - 1) ? 1.0f : 0.0f;
                float t00 = (float)upc[(size_t)yc0 * UPITCH + xc0] * mx0;
                float t01 = (float)upc[(size_t)yc0 * UPITCH + xc1] * mx1;
                float t10 = (float)upc[(size_t)yc1 * UPITCH + xc0] * mx0;
                float t11 = (float)upc[(size_t)yc1 * UPITCH + xc1] * mx1;
                float r0 = t00 + wx * (t01 - t00);
                float r1 = t10 + wx * (t11 - t10);
                s_wh[lwy * 82 + lwx] = (__fp16)(r0 * (1.0f - wyf) * my0 + r1 * wyf * my1);
            }
        }
    }
    __syncthreads();

    // packed filter registers
    float f[12];
#pragma unroll
    for (int i = 0; i < 12; ++i) f[i] = hz[i];
    h2 Fe[6];
#pragma unroll
    for (int i = 0; i < 6; ++i) { Fe[i][0] = (__fp16)f[2 * i]; Fe[i][1] = (__fp16)f[2 * i + 1]; }

    // phase 2: horizontal downsample via fdot2 on fp16 pairs -> s_m2 (aliases s_src)
    for (int i = tid; i < 74 * 16; i += 512) {
        int j = i & 15, lwy = i >> 4;
        const __fp16* r = &s_wh[lwy * 82 + 4 * j];
        h2 P0 = *(const h2*)(r + 0);
        h2 P1 = *(const h2*)(r + 2);
        h2 P2 = *(const h2*)(r + 4);
        h2 P3 = *(const h2*)(r + 6);
        h2 P4 = *(const h2*)(r + 8);
        h2 P5 = *(const h2*)(r + 10);
        h2 P6 = *(const h2*)(r + 12);
        float ev = __builtin_amdgcn_fdot2(P0, Fe[0],
                   __builtin_amdgcn_fdot2(P1, Fe[1],
                   __builtin_amdgcn_fdot2(P2, Fe[2],
                   __builtin_amdgcn_fdot2(P3, Fe[3],
                   __builtin_amdgcn_fdot2(P4, Fe[4],
                   __builtin_amdgcn_fdot2(P5, Fe[5], 0.0f, false), false), false), false), false), false);
        float od = __builtin_amdgcn_fdot2(P1, Fe[0],
                   __builtin_amdgcn_fdot2(P2, Fe[1],
                   __builtin_amdgcn_fdot2(P3, Fe[2],
                   __builtin_amdgcn_fdot2(P4, Fe[3],
                   __builtin_amdgcn_fdot2(P5, Fe[4],
                   __builtin_amdgcn_fdot2(P6, Fe[5], 0.0f, false), false), false), false), false), false);
        h2 sm; sm[0] = (__fp16)ev; sm[1] = (__fp16)od;
        s_m2[lwy * 17 + j] = sm;
    }
    __syncthreads();

    // phase 3: vertical downsample via perm-paired fdot2
    {
        int j = tid & 15, my = tid >> 4;    // 512 threads == 32x16 exactly
        const unsigned* m2u = (const unsigned*)s_m2;
        float ev = 0.0f, od = 0.0f;
#pragma unroll
        for (int t = 0; t < 12; t += 2) {
            unsigned ha = m2u[(2 * my + t) * 17 + j];
            unsigned hb = m2u[(2 * my + t + 1) * 17 + j];
            unsigned pe = __builtin_amdgcn_perm(hb, ha, 0x05040100u);  // (ha.lo, hb.lo)
            unsigned po = __builtin_amdgcn_perm(hb, ha, 0x07060302u);  // (ha.hi, hb.hi)
            h2 he; *(unsigned*)&he = pe;
            h2 ho; *(unsigned*)&ho = po;
            ev = __builtin_amdgcn_fdot2(he, Fe[t >> 1], ev, false);
            od = __builtin_amdgcn_fdot2(ho, Fe[t >> 1], od, false);
        }
        float2 o; o.x = ev; o.y = od;
        *(float2*)&out[(size_t)(ch0 + ch) * HO * WO + (size_t)(ty0 + my) * WO + (tx0 + 2 * j)] = o;
    }
}

// ---------------- launch ----------------
extern "C" void kernel_launch(void* const* d_in, const int* in_sizes, int n_in,
                              void* d_out, int out_size, void* d_ws, size_t ws_size,
                              hipStream_t stream) {
    const float* images = (const float*)d_in[0];
    const float* theta  = (const float*)d_in[1];
    const float* log_s  = (const float*)d_in[2];
    const float* tx     = (const float*)d_in[3];
    const float* ty     = (const float*)d_in[4];
    const float* hz     = (const float*)d_in[5];
    float* out = (float*)d_out;
    float* ws  = (float*)d_ws;

    // cn=32: single chunk (85.6 MB intermediate). Removes dispatch gaps; warpdn
    // 6144 blocks @ 3/CU = 8 full residency rounds (round-2 lesson: partial
    // rounds = 2x tail loss).
    int cn = 32;
    while (cn > 1) {
        size_t needed = 1024 + (size_t)cn * CH * CHELEMS * sizeof(__fp16);
        if (needed <= ws_size) break;
        cn >>= 1;
    }
    float* coef = ws;
    __fp16* upsb = (__fp16*)(ws + 256);

    hipLaunchKernelGGL(k_setup, dim3(1), dim3(32), 0, stream, theta, log_s, tx, ty, coef);

    const int TA = (HU + 63) / 64;    // 11
    for (int n0 = 0; n0 < NIMG; n0 += cn) {
        int nch = cn * CH;
        int ch0 = n0 * CH;
        hipLaunchKernelGGL(k_up2, dim3(TA, TA, nch), dim3(256), 0, stream,
                           images, hz, upsb, ch0);
        hipLaunchKernelGGL(k_warpdn, dim3(WO / 32, HO / 32, nch), dim3(512), 0, stream,
                           upsb, coef, hz, out, n0, ch0);
    }
}

// Round 10
// 95.395 us; speedup vs baseline: 1.0472x; 1.0472x over previous
//
#include <hip/hip_runtime.h>
#include <hip/hip_fp16.h>

// ---------------- problem constants ----------------
#define NIMG 32
#define CH   3
#define HIN  256
#define WIN  256
#define MARG 38          // 2*HZ_PAD + 32
#define HP   332         // HIN + 2*MARG
#define WP   332
#define HU   664         // 2*HP
#define WU   664
#define HO   256
#define WO   256

// plain fp16 upsampled intermediate, padded row pitch (cols 664..671 are zeros)
#define UPITCH  672
#define CHELEMS (664 * 672)

// LDS staging window for the warp (per 32x32 output tile)
#define PH 132            // max rows
#define PW 152            // max cols (19 x 8-elem slots), 8-aligned base
#define PWB (PW * 2)      // row pitch in bytes (304)

typedef __fp16 h2 __attribute__((ext_vector_type(2)));
typedef float  f2 __attribute__((ext_vector_type(2)));

// reflect (edge-excluding) for original 256-range, valid for r in [-255, 510]
__device__ __forceinline__ int refl(int r) {
    r = (r < 0) ? -r : r;
    return (r > 255) ? (510 - r) : r;
}

// ---------------- per-image affine coefficients ----------------
__global__ void k_setup(const float* __restrict__ th, const float* __restrict__ ls,
                        const float* __restrict__ txp, const float* __restrict__ typ,
                        float* __restrict__ coef) {
    int n = blockIdx.x * blockDim.x + threadIdx.x;
    if (n >= NIMG) return;
    float c  = cosf(th[n]);
    float sn = sinf(th[n]);
    float inv_s = 1.0f / expf(ls[n]);
    float tX = -txp[n] * (float)WIN;
    float tY = -typ[n] * (float)HIN;
    float A00 = inv_s * c,    A01 = inv_s * sn,  A02 = inv_s * (c * tX + sn * tY);
    float A10 = -inv_s * sn,  A11 = inv_s * c,   A12 = inv_s * (-sn * tX + c * tY);
    A02 *= 2.0f; A12 *= 2.0f;
    A02 += 0.5f * (A00 + A01) - 0.5f;
    A12 += 0.5f * (A10 + A11) - 0.5f;
    const float Wu = (float)HU, Hu = (float)HU;
    const float Wt = 524.0f, Ht = 524.0f;
    float B00 = A00 * (2.0f / Wu) * (Wt * 0.5f);
    float B01 = A01 * (2.0f / Wu) * (Ht * 0.5f);
    float B02 = A02 * (2.0f / Wu);
    float B10 = A10 * (2.0f / Hu) * (Wt * 0.5f);
    float B11 = A11 * (2.0f / Hu) * (Ht * 0.5f);
    float B12 = A12 * (2.0f / Hu);
    float cxx = B00 * Wu / Wt;
    float cxy = B01 * Wu / Ht;
    float cx0 = 0.5f * ((B00 * (1.0f / Wt - 1.0f) + B01 * (1.0f / Ht - 1.0f) + B02 + 1.0f) * Wu - 1.0f);
    float cyx = B10 * Hu / Wt;
    float cyy = B11 * Hu / Ht;
    float cy0 = 0.5f * ((B10 * (1.0f / Wt - 1.0f) + B11 * (1.0f / Ht - 1.0f) + B12 + 1.0f) * Hu - 1.0f);
    coef[n * 6 + 0] = cxx;
    coef[n * 6 + 1] = cxy;
    coef[n * 6 + 2] = cx0;
    coef[n * 6 + 3] = cyx;
    coef[n * 6 + 4] = cyy;
    coef[n * 6 + 5] = cy0;
}

__device__ __forceinline__ unsigned hbits(float a, float b) {
    __half2 h = __floats2half2_rn(a, b);
    return *(unsigned*)&h;
}

// ---------------- KA: fused reflect-pad + 2x upsample -> plain fp16 (padded pitch) ----------------
// Round-7 structure (best measured: f32 s_mid, 2-pass float4 stage-3, 2-way-free banks)
// + stage-1 interior fast path (40% of blocks, block-uniform: no reflect/bounds).
__global__ void __launch_bounds__(256) k_up2(const float* __restrict__ img,
                                             const float* __restrict__ hz,
                                             __fp16* __restrict__ ups, int ch0) {
    __shared__ float s_in[38][40];    // 38 rows x 39 cols used
    __shared__ float s_mid[38][68];   // cols 0..65 used
    int ch  = blockIdx.z;
    int ty0 = blockIdx.y * 64;
    int tx0 = blockIdx.x * 64;
    int jy0 = (ty0 >> 1) - 3;
    int jx0 = (tx0 >> 1) - 3;
    int tid = threadIdx.x;
    float fs[12];                     // 2*f[i] (exact scaling)
#pragma unroll
    for (int i = 0; i < 12; ++i) fs[i] = 2.0f * hz[i];
    const float* base = img + (size_t)(ch0 + ch) * HIN * WIN;

    // stage 1: padded input patch (38 x 39), zero outside [0,332)^2
    if (jy0 >= 38 && jy0 <= 256 && jx0 >= 38 && jx0 <= 255) {
        // interior: patch maps 1:1 to input, no reflect/bounds (block-uniform branch)
        const float* bsrc = base + (jy0 - MARG) * WIN + (jx0 - MARG);
        for (int i = tid; i < 38 * 39; i += 256) {
            int ly = i / 39, lx = i - ly * 39;
            s_in[ly][lx] = bsrc[ly * WIN + lx];
        }
    } else {
        for (int i = tid; i < 38 * 39; i += 256) {
            int ly = i / 39, lx = i - ly * 39;
            int gy = jy0 + ly, gx = jx0 + lx;
            float v = 0.0f;
            if (gy >= 0 && gy < HP && gx >= 0 && gx < WP)
                v = base[refl(gy - MARG) * WIN + refl(gx - MARG)];
            s_in[ly][lx] = v;
        }
    }
    __syncthreads();

    // stage 2: horizontal upsample, row-pairs packed: item = (ly pair, j), 19x33
    for (int i = tid; i < 19 * 33; i += 256) {
        int j = i % 33, lp = i / 33;
        int ly = 2 * lp;
        const float* ra = &s_in[ly][j];
        const float* rb = &s_in[ly + 1][j];
        f2 ev = {0.0f, 0.0f}, od = {0.0f, 0.0f};   // .x = row ly, .y = row ly+1
#pragma unroll
        for (int t = 0; t < 6; ++t) {
            f2 ta; ta.x = ra[t];     ta.y = rb[t];       // ds_read2_b32 (offsets 40 apart)
            f2 tb; tb.x = ra[t + 1]; tb.y = rb[t + 1];
            ev += fs[11 - 2 * t] * ta;
            od += fs[10 - 2 * t] * tb;
        }
        f2 lo; lo.x = ev.x; lo.y = od.x;
        f2 hi; hi.x = ev.y; hi.y = od.y;
        *(f2*)&s_mid[ly][2 * j]     = lo;
        *(f2*)&s_mid[ly + 1][2 * j] = hi;
    }
    __syncthreads();

    // stage 3: vertical upsample; packed across columns; 8B stores (2-way banks: free)
    int qx = tid & 15;
    int mg = tid >> 4;
    int gx0 = tx0 + 4 * qx;
    __fp16* upch = ups + (size_t)ch * CHELEMS;
#pragma unroll
    for (int pi = 0; pi < 2; ++pi) {
        int m = mg + pi * 16;
        int gy = ty0 + 2 * m;
        if (gy < HU) {
            if (gx0 + 3 < WU) {
                float4 r0 = *(const float4*)&s_mid[m + 0][4 * qx];
                float4 r1 = *(const float4*)&s_mid[m + 1][4 * qx];
                float4 r2 = *(const float4*)&s_mid[m + 2][4 * qx];
                float4 r3 = *(const float4*)&s_mid[m + 3][4 * qx];
                float4 r4 = *(const float4*)&s_mid[m + 4][4 * qx];
                float4 r5 = *(const float4*)&s_mid[m + 5][4 * qx];
                float4 r6 = *(const float4*)&s_mid[m + 6][4 * qx];
                f2 a0; a0.x = r0.x; a0.y = r0.y;  f2 b0; b0.x = r0.z; b0.y = r0.w;
                f2 a1; a1.x = r1.x; a1.y = r1.y;  f2 b1; b1.x = r1.z; b1.y = r1.w;
                f2 a2; a2.x = r2.x; a2.y = r2.y;  f2 b2; b2.x = r2.z; b2.y = r2.w;
                f2 a3; a3.x = r3.x; a3.y = r3.y;  f2 b3; b3.x = r3.z; b3.y = r3.w;
                f2 a4; a4.x = r4.x; a4.y = r4.y;  f2 b4; b4.x = r4.z; b4.y = r4.w;
                f2 a5; a5.x = r5.x; a5.y = r5.y;  f2 b5; b5.x = r5.z; b5.y = r5.w;
                f2 a6; a6.x = r6.x; a6.y = r6.y;  f2 b6; b6.x = r6.z; b6.y = r6.w;
                f2 e01 = fs[11]*a0 + fs[9]*a1 + fs[7]*a2 + fs[5]*a3 + fs[3]*a4 + fs[1]*a5;
                f2 e23 = fs[11]*b0 + fs[9]*b1 + fs[7]*b2 + fs[5]*b3 + fs[3]*b4 + fs[1]*b5;
                f2 o01 = fs[10]*a1 + fs[8]*a2 + fs[6]*a3 + fs[4]*a4 + fs[2]*a5 + fs[0]*a6;
                f2 o23 = fs[10]*b1 + fs[8]*b2 + fs[6]*b3 + fs[4]*b4 + fs[2]*b5 + fs[0]*b6;
                uint2 qe, qo;
                qe.x = hbits(e01.x, e01.y); qe.y = hbits(e23.x, e23.y);
                qo.x = hbits(o01.x, o01.y); qo.y = hbits(o23.x, o23.y);
                *(uint2*)&upch[(size_t)gy * UPITCH + gx0]       = qe;
                *(uint2*)&upch[(size_t)(gy + 1) * UPITCH + gx0] = qo;
            } else if (gx0 >= WU && gx0 < UPITCH) {
                uint2 z; z.x = 0u; z.y = 0u;   // zero pad cols 664..671
                *(uint2*)&upch[(size_t)gy * UPITCH + gx0]       = z;
                *(uint2*)&upch[(size_t)(gy + 1) * UPITCH + gx0] = z;
            }
        }
    }
}

// ---------------- gather helpers ----------------
// act-free: out-of-tile samples (lwy/lwx in [74,80)) write into s_wh's padding
// (max waddr 79*82+79 = 6557 < 6560), which ph2 never reads (rows<74, cols<=73).
struct GS {
    int a_rd;        // clamped LDS byte addr of (ly, e) halfword pair
    unsigned sh;     // alignbit shift (0 or 16)
    int waddr;       // s_wh element index
    float wyf;       // y lerp weight
    h2 wv;           // packed (1-wx, wx)
};

__device__ __forceinline__ GS gmake(float rx, float ry, int wadd) {
    GS g;
    int lx = (int)rx;                               // trunc == floor (rx>=0 when in-tile)
    int ly = (int)ry;
    float wx = __builtin_amdgcn_fractf(rx);         // == rx - floor(rx); exact, 1 instr
    g.wyf    = __builtin_amdgcn_fractf(ry);
    unsigned a = (unsigned)(ly * PWB + (lx & ~1) * 2);
    const unsigned amax = (PH - 1) * PWB - 8;
    g.a_rd = (int)(a > amax ? amax : a);            // single v_min_u32: negatives wrap huge
    g.sh = ((unsigned)lx & 1u) << 4;
    g.waddr = wadd;
    g.wv = __builtin_amdgcn_cvt_pkrtz(1.0f - wx, wx);
    return g;
}

__device__ __forceinline__ void gfinish(const GS& g, unsigned w0, unsigned w1,
                                        unsigned w2, unsigned w3, __fp16* s_wh) {
    unsigned u0 = __builtin_amdgcn_alignbit(w1, w0, g.sh);
    unsigned u1 = __builtin_amdgcn_alignbit(w3, w2, g.sh);
    h2 h0; *(unsigned*)&h0 = u0;
    h2 h1; *(unsigned*)&h1 = u1;
    float r0 = __builtin_amdgcn_fdot2(h0, g.wv, 0.0f, false);
    float r1 = __builtin_amdgcn_fdot2(h1, g.wv, 0.0f, false);
    s_wh[g.waddr] = (__fp16)(r0 + g.wyf * (r1 - r0));   // unconditional
}

// ---------------- KB: LDS-staged bilinear warp + 2x downsample (512 threads) ----------------
__global__ void __launch_bounds__(512) k_warpdn(const __fp16* __restrict__ ups,
                                                const float* __restrict__ coef,
                                                const float* __restrict__ hz,
                                                float* __restrict__ out,
                                                int n0, int ch0) {
    __shared__ __align__(16) unsigned char s_raw[PH * PWB];      // 40.1 KB
    __shared__ __fp16 s_wh[80 * 82];                             // 13.1 KB
    __fp16* s_src = (__fp16*)s_raw;
    h2*     s_m2  = (h2*)s_raw;      // aliases s_src (disjoint live ranges)

    int ch  = blockIdx.z;
    int ty0 = blockIdx.y * 32;
    int tx0 = blockIdx.x * 32;
    int tid = threadIdx.x;
    const float* cf = coef + (size_t)(n0 + ch / CH) * 6;
    float cxx = cf[0], cxy = cf[1], cx0 = cf[2];
    float cyx = cf[3], cyy = cf[4], cy0 = cf[5];
    const __fp16* upc = ups + (size_t)ch * CHELEMS;
    const unsigned short* us = (const unsigned short*)upc;
    int wy0 = 2 * ty0 + 1, wx0 = 2 * tx0 + 1;
    float wx0f = (float)wx0, wy0f = (float)wy0;

    // source bbox from tile corners (affine -> corners bound everything)
    float ix00 = cxx * wx0f + cxy * wy0f + cx0;
    float iy00 = cyx * wx0f + cyy * wy0f + cy0;
    float dxx = cxx * 73.0f, dxy = cxy * 73.0f;
    float dyx = cyx * 73.0f, dyy = cyy * 73.0f;
    float ixmin = ix00 + fminf(dxx, 0.0f) + fminf(dxy, 0.0f);
    float ixmax = ix00 + fmaxf(dxx, 0.0f) + fmaxf(dxy, 0.0f);
    float iymin = iy00 + fminf(dyx, 0.0f) + fminf(dyy, 0.0f);
    float iymax = iy00 + fmaxf(dyx, 0.0f) + fmaxf(dyy, 0.0f);
    int x_lo = (int)floorf(ixmin) - 1;
    int x_base = x_lo & ~7;
    int x_hi = (int)floorf(ixmax) + 2;
    int y_lo = (int)floorf(iymin) - 1;
    int y_hi = (int)floorf(iymax) + 2;
    int Rn = y_hi - y_lo + 1;
    int Wn = x_hi - x_base + 1;
    bool ldsok = (Rn <= PH) && (Wn <= PW);

    int wave = __builtin_amdgcn_readfirstlane(tid >> 6);   // 0..7
    int lane = tid & 63;
    int ply = lane >> 3, plx = lane & 7;
    float ix_l = cxx * (float)(wx0 + plx) + cxy * (float)(wy0 + ply) + cx0;
    float iy_l = cyx * (float)(wx0 + plx) + cyy * (float)(wy0 + ply) + cy0;
    float c8xx = 8.0f * cxx, c8xy = 8.0f * cxy;
    float c8yx = 8.0f * cyx, c8yy = 8.0f * cyy;

    if (ldsok) {
        // ---- stage bbox into LDS, dense per-lane (row,slot) mapping ----
        int spr = (Wn + 7) >> 3;                  // slots per row, <= 19
        int rpp = 64 / spr;                       // rows per wave-pass
        float rcp = 1.0f / (float)spr;
        int lrow = (int)((float)lane * rcp);
        if (lrow * spr > lane) lrow--;
        if ((lrow + 1) * spr <= lane) lrow++;
        int lslot = lane - lrow * spr;
        // interior: every staged 16B chunk is in-bounds (block-uniform branch)
        bool sint = (y_lo >= 0) && (y_lo + Rn <= HU) &&
                    (x_base >= 0) && (x_base + spr * 8 <= UPITCH);
        if (lrow < rpp) {
            int gx = x_base + lslot * 8;
            if (sint) {
                const unsigned char* src = (const unsigned char*)
                    &upc[(size_t)(y_lo + wave * rpp + lrow) * UPITCH + gx];
                for (int row = wave * rpp + lrow; row < Rn; row += 8 * rpp) {
                    *(uint4*)&s_src[row * PW + lslot * 8] = *(const uint4*)src;
                    src += (size_t)(8 * rpp) * UPITCH * sizeof(__fp16);
                }
            } else {
                for (int row = wave * rpp + lrow; row < Rn; row += 8 * rpp) {
                    int gy = y_lo + row;
                    uint4 val;
                    if (gy >= 0 && gy < HU && gx >= 0 && gx <= UPITCH - 8) {
                        val = *(const uint4*)&upc[(size_t)gy * UPITCH + gx];
                    } else if (gy >= 0 && gy < HU) {
                        unsigned part[4];
#pragma unroll
                        for (int k = 0; k < 4; ++k) {
                            int ga = gx + 2 * k, gb = ga + 1;
                            unsigned lo = (ga >= 0 && ga < WU) ? (unsigned)us[(size_t)gy * UPITCH + ga] : 0u;
                            unsigned hi = (gb >= 0 && gb < WU) ? (unsigned)us[(size_t)gy * UPITCH + gb] : 0u;
                            part[k] = lo | (hi << 16);
                        }
                        val.x = part[0]; val.y = part[1]; val.z = part[2]; val.w = part[3];
                    } else {
                        val.x = 0u; val.y = 0u; val.z = 0u; val.w = 0u;
                    }
                    *(uint4*)&s_src[row * PW + lslot * 8] = val;
                }
            }
        }
        __syncthreads();

        // ---- warp from LDS: depth-2 pipelined, column-major incremental stepping ----
        float ixb = ix_l - (float)x_base;
        float iyb = iy_l - (float)y_lo;
        int wbase = ply * 82 + plx;
        float rx = ixb + (float)wave * c8xy;          // px=0, py=wave
        float ry = iyb + (float)wave * c8yy;
        int wadd = wbase + wave * 656;
        int py = wave;
        const float sxA = 8.0f * c8xy,            syA = 8.0f * c8yy;
        const float sxB = c8xx - 2.0f * c8xy,     syB = c8yx - 2.0f * c8yy;
        int tc = (wave < 4) ? 13 : 12;            // idx = wave + 8k < 100

        GS g0 = gmake(rx, ry, wadd);
        {   int pyn = py + 8;
            if (pyn >= 10) { rx += sxB; ry += syB; wadd += 8 - 2 * 656; py = pyn - 10; }
            else           { rx += sxA; ry += syA; wadd += 8 * 656;     py = pyn; } }
        const unsigned* q0 = (const unsigned*)(s_raw + g0.a_rd);
        unsigned a0 = q0[0], a1 = q0[1], a2 = q0[PWB / 4], a3 = q0[PWB / 4 + 1];
        for (int k = 1; k < tc; ++k) {
            GS g1 = gmake(rx, ry, wadd);
            {   int pyn = py + 8;
                if (pyn >= 10) { rx += sxB; ry += syB; wadd += 8 - 2 * 656; py = pyn - 10; }
                else           { rx += sxA; ry += syA; wadd += 8 * 656;     py = pyn; } }
            const unsigned* q1 = (const unsigned*)(s_raw + g1.a_rd);
            unsigned b0 = q1[0], b1 = q1[1], b2 = q1[PWB / 4], b3 = q1[PWB / 4 + 1];
            gfinish(g0, a0, a1, a2, a3, s_wh);
            g0 = g1; a0 = b0; a1 = b1; a2 = b2; a3 = b3;
        }
        gfinish(g0, a0, a1, a2, a3, s_wh);
    } else {
        // ---- fallback: guarded global gather (rare: bbox too large) ----
        for (int pp = wave; pp < 100; pp += 8) {
            int py = (pp * 205) >> 11;
            int px = pp - py * 10;
            int lwy = py * 8 + ply;
            int lwx = px * 8 + plx;
            if (lwy < 74 && lwx < 74) {
                float ix = ix_l + (float)px * c8xx + (float)py * c8xy;
                float iy = iy_l + (float)px * c8yx + (float)py * c8yy;
                float fx = floorf(ix), fy = floorf(iy);
                float wx = ix - fx, wyf = iy - fy;
                int x0 = (int)fx, y0 = (int)fy;
                int xc0 = min(max(x0, 0), WU - 1);
                int xc1 = min(max(x0 + 1, 0), WU - 1);
                int yc0 = min(max(y0, 0), HU - 1);
                int yc1 = min(max(y0 + 1, 0), HU - 1);
                float mx0 = (x0 >= 0 && x0 < WU) ? 1.0f : 0.0f;
                float mx1 = (x0 >= -1 && x0 < WU - 1) ? 1.0f : 0.0f;
                float my0 = (y0 >= 0 && y0 < HU) ? 1.0f : 0.0f;
                float my1 = (y0 >= -1 && y0 < HU - 1) ? 1.0f : 0.0f;
                float t00 = (float)upc[(size_t)yc0 * UPITCH + xc0] * mx0;
                float t01 = (float)upc[(size_t)yc0 * UPITCH + xc1] * mx1;
                float t10 = (float)upc[(size_t)yc1 * UPITCH + xc0] * mx0;
                float t11 = (float)upc[(size_t)yc1 * UPITCH + xc1] * mx1;
                float r0 = t00 + wx * (t01 - t00);
                float r1 = t10 + wx * (t11 - t10);
                s_wh[lwy * 82 + lwx] = (__fp16)(r0 * (1.0f - wyf) * my0 + r1 * wyf * my1);
            }
        }
    }
    __syncthreads();

    // packed filter registers
    float f[12];
#pragma unroll
    for (int i = 0; i < 12; ++i) f[i] = hz[i];
    h2 Fe[6];
#pragma unroll
    for (int i = 0; i < 6; ++i) { Fe[i][0] = (__fp16)f[2 * i]; Fe[i][1] = (__fp16)f[2 * i + 1]; }

    // phase 2: horizontal downsample via fdot2 on fp16 pairs -> s_m2 (aliases s_src)
    for (int i = tid; i < 74 * 16; i += 512) {
        int j = i & 15, lwy = i >> 4;
        const __fp16* r = &s_wh[lwy * 82 + 4 * j];
        h2 P0 = *(const h2*)(r + 0);
        h2 P1 = *(const h2*)(r + 2);
        h2 P2 = *(const h2*)(r + 4);
        h2 P3 = *(const h2*)(r + 6);
        h2 P4 = *(const h2*)(r + 8);
        h2 P5 = *(const h2*)(r + 10);
        h2 P6 = *(const h2*)(r + 12);
        float ev = __builtin_amdgcn_fdot2(P0, Fe[0],
                   __builtin_amdgcn_fdot2(P1, Fe[1],
                   __builtin_amdgcn_fdot2(P2, Fe[2],
                   __builtin_amdgcn_fdot2(P3, Fe[3],
                   __builtin_amdgcn_fdot2(P4, Fe[4],
                   __builtin_amdgcn_fdot2(P5, Fe[5], 0.0f, false), false), false), false), false), false);
        float od = __builtin_amdgcn_fdot2(P1, Fe[0],
                   __builtin_amdgcn_fdot2(P2, Fe[1],
                   __builtin_amdgcn_fdot2(P3, Fe[2],
                   __builtin_amdgcn_fdot2(P4, Fe[3],
                   __builtin_amdgcn_fdot2(P5, Fe[4],
                   __builtin_amdgcn_fdot2(P6, Fe[5], 0.0f, false), false), false), false), false), false);
        h2 sm; sm[0] = (__fp16)ev; sm[1] = (__fp16)od;
        s_m2[lwy * 17 + j] = sm;
    }
    __syncthreads();

    // phase 3: vertical downsample via perm-paired fdot2
    {
        int j = tid & 15, my = tid >> 4;    // 512 threads == 32x16 exactly
        const unsigned* m2u = (const unsigned*)s_m2;
        float ev = 0.0f, od = 0.0f;
#pragma unroll
        for (int t = 0; t < 12; t += 2) {
            unsigned ha = m2u[(2 * my + t) * 17 + j];
            unsigned hb = m2u[(2 * my + t + 1) * 17 + j];
            unsigned pe = __builtin_amdgcn_perm(hb, ha, 0x05040100u);  // (ha.lo, hb.lo)
            unsigned po = __builtin_amdgcn_perm(hb, ha, 0x07060302u);  // (ha.hi, hb.hi)
            h2 he; *(unsigned*)&he = pe;
            h2 ho; *(unsigned*)&ho = po;
            ev = __builtin_amdgcn_fdot2(he, Fe[t >> 1], ev, false);
            od = __builtin_amdgcn_fdot2(ho, Fe[t >> 1], od, false);
        }
        float2 o; o.x = ev; o.y = od;
        *(float2*)&out[(size_t)(ch0 + ch) * HO * WO + (size_t)(ty0 + my) * WO + (tx0 + 2 * j)] = o;
    }
}

// ---------------- launch ----------------
extern "C" void kernel_launch(void* const* d_in, const int* in_sizes, int n_in,
                              void* d_out, int out_size, void* d_ws, size_t ws_size,
                              hipStream_t stream) {
    const float* images = (const float*)d_in[0];
    const float* theta  = (const float*)d_in[1];
    const float* log_s  = (const float*)d_in[2];
    const float* tx     = (const float*)d_in[3];
    const float* ty     = (const float*)d_in[4];
    const float* hz     = (const float*)d_in[5];
    float* out = (float*)d_out;
    float* ws  = (float*)d_ws;

    // cn=32: single chunk (85.6 MB intermediate). Removes dispatch gaps; warpdn
    // 6144 blocks @ 3/CU = 8 full residency rounds (round-2 lesson: partial
    // rounds = 2x tail loss).
    int cn = 32;
    while (cn > 1) {
        size_t needed = 1024 + (size_t)cn * CH * CHELEMS * sizeof(__fp16);
        if (needed <= ws_size) break;
        cn >>= 1;
    }
    float* coef = ws;
    __fp16* upsb = (__fp16*)(ws + 256);

    hipLaunchKernelGGL(k_setup, dim3(1), dim3(32), 0, stream, theta, log_s, tx, ty, coef);

    const int TA = (HU + 63) / 64;    // 11
    for (int n0 = 0; n0 < NIMG; n0 += cn) {
        int nch = cn * CH;
        int ch0 = n0 * CH;
        hipLaunchKernelGGL(k_up2, dim3(TA, TA, nch), dim3(256), 0, stream,
                           images, hz, upsb, ch0);
        hipLaunchKernelGGL(k_warpdn, dim3(WO / 32, HO / 32, nch), dim3(512), 0, stream,
                           upsb, coef, hz, out, n0, ch0);
    }
}